// Round 5
// baseline (792.589 us; speedup 1.0000x reference)
//
#include <hip/hip_runtime.h>
#include <hip/hip_bf16.h>
#include <climits>

#define N_NODES   100000
#define N_EDGES   1600000
#define D         64
#define N_GRAPHS  32
#define N_CLASSES 40
#define N_TILES   (N_NODES / 16)   // 6250 row-tiles of 16
#define TPW       2                // row-tiles per wave
#define GEMM_WAVES ((N_TILES + TPW - 1) / TPW)        // 3125
#define GEMM_BLOCKS ((GEMM_WAVES + 3) / 4)            // 782
#define POOL_NPW  32               // nodes per wave in k_pool

// bucketed edge partition
#define BKT_SHIFT 7
#define BKT_NODES 128
#define NB        ((N_NODES + BKT_NODES - 1) / BKT_NODES)   // 782
#define CHUNK     4096
#define NCHUNK    ((N_EDGES + CHUNK - 1) / CHUNK)           // 391
#define EPT       (CHUNK / 256)                             // 16 edges/thread

typedef __bf16 bf16_t;
typedef bf16_t bf16x8 __attribute__((ext_vector_type(8)));
typedef float  f32x4  __attribute__((ext_vector_type(4)));

// Monotone bijection float -> int (order-preserving for signed int compare).
__device__ __forceinline__ int f2ord(float f) {
    int i = __float_as_int(f);
    return (i >= 0) ? i : (i ^ 0x7FFFFFFF);
}
__device__ __forceinline__ float ord2f(int i) {
    int j = (i >= 0) ? i : (i ^ 0x7FFFFFFF);
    return __int_as_float(j);
}

__global__ __launch_bounds__(256) void k_fill(int* __restrict__ p, long n, int v) {
    long i = (long)blockIdx.x * blockDim.x + threadIdx.x;
    long stride = (long)gridDim.x * blockDim.x;
    for (; i < n; i += stride) p[i] = v;
}

// ---------------- weight prep: wcat[l][n][k] = (n<64 ? tw : pw)[l][k][n%64], bf16 ----------------
__global__ __launch_bounds__(256) void k_prep(
    const float* __restrict__ tw, const float* __restrict__ pw,
    const float* __restrict__ tb, const float* __restrict__ pb,
    bf16_t* __restrict__ wcat, float* __restrict__ bcat)
{
    const int i = blockIdx.x * 256 + threadIdx.x;
    if (i < 3 * 128 * 64) {
        const int l = i >> 13;
        const int rem = i & 8191;
        const int n = rem >> 6;
        const int k = rem & 63;
        const float v = (n < D) ? tw[l * 4096 + k * D + n] : pw[l * 4096 + k * D + (n - D)];
        wcat[i] = (bf16_t)v;
    }
    if (i < 3 * D) bcat[i] = tb[i] + pb[i];
}

// ---------------- bucket partition of edges by dst>>7 ----------------

__global__ __launch_bounds__(256) void k_bkt_hist(
    const int* __restrict__ dst, int* __restrict__ bktcnt)
{
    __shared__ int l[NB];
    for (int i = threadIdx.x; i < NB; i += 256) l[i] = 0;
    __syncthreads();
    const int base = blockIdx.x * CHUNK;
    #pragma unroll
    for (int i = 0; i < EPT; ++i) {
        const int e = base + i * 256 + threadIdx.x;
        if (e < N_EDGES) atomicAdd(&l[dst[e] >> BKT_SHIFT], 1);
    }
    __syncthreads();
    for (int i = threadIdx.x; i < NB; i += 256)
        if (l[i]) atomicAdd(&bktcnt[i], l[i]);
}

// Exclusive scan of NB bucket counts (1 block); also inits gcur and boff[NB].
__global__ __launch_bounds__(256) void k_bkt_scan(
    const int* __restrict__ bktcnt, int* __restrict__ boff, int* __restrict__ gcur)
{
    __shared__ int s[256];
    const int t = threadIdx.x;
    int v[4], sum = 0;
    #pragma unroll
    for (int i = 0; i < 4; ++i) {
        const int idx = t * 4 + i;
        v[i] = (idx < NB) ? bktcnt[idx] : 0;
        sum += v[i];
    }
    s[t] = sum;
    __syncthreads();
    #pragma unroll
    for (int off = 1; off < 256; off <<= 1) {
        int x = (t >= off) ? s[t - off] : 0;
        __syncthreads();
        s[t] += x;
        __syncthreads();
    }
    int run = s[t] - sum;
    #pragma unroll
    for (int i = 0; i < 4; ++i) {
        const int idx = t * 4 + i;
        if (idx < NB) {
            boff[idx] = run;
            gcur[idx] = run;
        }
        run += v[i];
    }
    if (t == 255) boff[NB] = N_EDGES;
}

// Pass A: scatter edges into bucket regions. Block-local ranks via LDS, one global
// atomicAdd per (block,bucket) reserves a contiguous run -> write locality.
// Packed edge: (dst & 127) << 17 | src   (src < 2^17).
__global__ __launch_bounds__(256) void k_bkt_scatter(
    const int* __restrict__ src, const int* __restrict__ dst,
    int* __restrict__ gcur, unsigned* __restrict__ bke)
{
    __shared__ int lcnt[NB];
    __shared__ int gb[NB];
    for (int i = threadIdx.x; i < NB; i += 256) lcnt[i] = 0;
    __syncthreads();
    const int base = blockIdx.x * CHUNK;
    unsigned pk[EPT], br[EPT];
    #pragma unroll
    for (int i = 0; i < EPT; ++i) {
        const int e = base + i * 256 + threadIdx.x;
        if (e < N_EDGES) {
            const int d = dst[e];
            const int b = d >> BKT_SHIFT;
            const int r = atomicAdd(&lcnt[b], 1);
            pk[i] = ((unsigned)(d & (BKT_NODES - 1)) << 17) | (unsigned)src[e];
            br[i] = ((unsigned)b << 13) | (unsigned)r;   // r < 4096
        } else {
            br[i] = 0xFFFFFFFFu;
        }
    }
    __syncthreads();
    for (int i = threadIdx.x; i < NB; i += 256) {
        const int c = lcnt[i];
        gb[i] = c ? atomicAdd(&gcur[i], c) : 0;
    }
    __syncthreads();
    #pragma unroll
    for (int i = 0; i < EPT; ++i) {
        if (br[i] != 0xFFFFFFFFu) {
            const int b = br[i] >> 13;
            const int r = br[i] & 8191;
            bke[gb[b] + r] = pk[i];
        }
    }
}

// ---------------- fused node GEMM via MFMA: t = bf16(A@tw), q = bf16(A@pw + b - A@tw) ----------------
template <bool FROM_F32>
__global__ __launch_bounds__(256) void k_gemm_mfma(
    const float* __restrict__ hf, const bf16_t* __restrict__ hb,
    const bf16_t* __restrict__ wcat,  // [128][64] this layer
    const float* __restrict__ bcat,   // [64] this layer
    bf16_t* __restrict__ t, bf16_t* __restrict__ q)
{
    const int lane = threadIdx.x & 63;
    const int wid  = blockIdx.x * 4 + (threadIdx.x >> 6);
    const int r16  = lane & 15;
    const int kg   = lane >> 4;   // 0..3
    const int koff = kg * 8;

    bf16x8 bfrag[8][2];
    #pragma unroll
    for (int c = 0; c < 8; ++c)
        #pragma unroll
        for (int s = 0; s < 2; ++s)
            bfrag[c][s] = *(const bf16x8*)&wcat[(c * 16 + r16) * D + s * 32 + koff];

    float bias[4];
    #pragma unroll
    for (int c = 0; c < 4; ++c) bias[c] = bcat[c * 16 + r16];

    #pragma unroll
    for (int tt = 0; tt < TPW; ++tt) {
        const int tile = wid * TPW + tt;
        if (tile >= N_TILES) return;
        const long rowbase = (long)tile * 16;
        const long arow = rowbase + r16;

        bf16x8 afrag[2];
        if (FROM_F32) {
            #pragma unroll
            for (int s = 0; s < 2; ++s) {
                const f32x4 v0 = *(const f32x4*)&hf[arow * D + s * 32 + koff];
                const f32x4 v1 = *(const f32x4*)&hf[arow * D + s * 32 + koff + 4];
                bf16x8 a;
                a[0] = (bf16_t)v0[0]; a[1] = (bf16_t)v0[1];
                a[2] = (bf16_t)v0[2]; a[3] = (bf16_t)v0[3];
                a[4] = (bf16_t)v1[0]; a[5] = (bf16_t)v1[1];
                a[6] = (bf16_t)v1[2]; a[7] = (bf16_t)v1[3];
                afrag[s] = a;
            }
        } else {
            afrag[0] = *(const bf16x8*)&hb[arow * D + koff];
            afrag[1] = *(const bf16x8*)&hb[arow * D + 32 + koff];
        }

        const f32x4 zero = {0.0f, 0.0f, 0.0f, 0.0f};
        f32x4 acc[8];
        #pragma unroll
        for (int c = 0; c < 8; ++c) {
            acc[c] = __builtin_amdgcn_mfma_f32_16x16x32_bf16(afrag[0], bfrag[c][0], zero, 0, 0, 0);
            acc[c] = __builtin_amdgcn_mfma_f32_16x16x32_bf16(afrag[1], bfrag[c][1], acc[c], 0, 0, 0);
        }

        #pragma unroll
        for (int c = 0; c < 4; ++c) {
            #pragma unroll
            for (int j = 0; j < 4; ++j) {
                const long R = rowbase + kg * 4 + j;
                const int f = c * 16 + r16;
                t[R * D + f] = (bf16_t)acc[c][j];
                q[R * D + f] = (bf16_t)(acc[c + 4][j] - acc[c][j] + bias[c]);
            }
        }
    }
}

// ---------------- bucketed edge max: one block per 128-node bucket ----------------
__global__ __launch_bounds__(256) void k_edge_bkt(
    const int* __restrict__ boff, const unsigned* __restrict__ bke,
    const bf16_t* __restrict__ t, const bf16_t* __restrict__ q,
    bf16_t* __restrict__ agg)
{
    __shared__ int acc[BKT_NODES * D];   // 32 KB
    const int b = blockIdx.x;
    for (int i = threadIdx.x; i < BKT_NODES * D; i += 256) acc[i] = INT_MIN;
    __syncthreads();

    const int lane = threadIdx.x & 63;
    const int wv   = threadIdx.x >> 6;
    const int beg = boff[b];
    const int end = boff[b + 1];

    for (int e0 = beg + wv * 4; e0 < end; e0 += 16) {
        unsigned pks[4];
        float    vs[4];
        const int cnt = (end - e0 < 4) ? (end - e0) : 4;
        #pragma unroll
        for (int j = 0; j < 4; ++j)
            if (j < cnt) pks[j] = bke[e0 + j];
        #pragma unroll
        for (int j = 0; j < 4; ++j)
            if (j < cnt) vs[j] = (float)t[(long)(pks[j] & 0x1FFFF) * D + lane];
        #pragma unroll
        for (int j = 0; j < 4; ++j)
            if (j < cnt) atomicMax(&acc[(pks[j] >> 17) * D + lane], f2ord(vs[j]));
    }
    __syncthreads();

    const int node0 = b * BKT_NODES;
    for (int i = wv; i < BKT_NODES; i += 4) {
        const int node = node0 + i;
        if (node >= N_NODES) break;
        const int a = acc[i * D + lane];
        const float out = (a == INT_MIN) ? 0.0f
                        : ord2f(a) + (float)q[(long)node * D + lane];
        agg[(long)node * D + lane] = (bf16_t)out;
    }
}

// ---------------- readout ----------------
__global__ __launch_bounds__(256) void k_pool(
    const bf16_t* __restrict__ agg, const int* __restrict__ gid,
    int* __restrict__ hg)
{
    const int lane = threadIdx.x & 63;
    const int wave = threadIdx.x >> 6;
    const int n0 = (blockIdx.x * 4 + wave) * POOL_NPW;
    if (n0 >= N_NODES) return;
    const int nend = (n0 + POOL_NPW < N_NODES) ? n0 + POOL_NPW : N_NODES;
    int cur = gid[n0];
    float m = -INFINITY;
    for (int n = n0; n < nend; ++n) {
        const int g = gid[n];
        if (g != cur) {
            atomicMax(&hg[cur * D + lane], f2ord(m));
            cur = g;
            m = -INFINITY;
        }
        m = fmaxf(m, (float)agg[(long)n * D + lane]);
    }
    atomicMax(&hg[cur * D + lane], f2ord(m));
}

__global__ __launch_bounds__(256) void k_cls(
    const int* __restrict__ hg, const float* __restrict__ w,
    const float* __restrict__ b, float* __restrict__ out)
{
    __shared__ float s_h[N_GRAPHS * D];
    __shared__ float s_w[D * N_CLASSES];
    __shared__ float s_b[N_CLASSES];
    for (int i = threadIdx.x; i < N_GRAPHS * D; i += 256) s_h[i] = ord2f(hg[i]);
    for (int i = threadIdx.x; i < D * N_CLASSES; i += 256) s_w[i] = w[i];
    if (threadIdx.x < N_CLASSES) s_b[threadIdx.x] = b[threadIdx.x];
    __syncthreads();
    for (int o = threadIdx.x; o < N_GRAPHS * N_CLASSES; o += 256) {
        const int g = o / N_CLASSES;
        const int c = o % N_CLASSES;
        float acc = s_b[c];
        #pragma unroll
        for (int k = 0; k < D; ++k)
            acc = fmaf(s_h[g * D + k], s_w[k * N_CLASSES + c], acc);
        out[o] = acc;
    }
}

extern "C" void kernel_launch(void* const* d_in, const int* in_sizes, int n_in,
                              void* d_out, int out_size, void* d_ws, size_t ws_size,
                              hipStream_t stream) {
    const float* h       = (const float*)d_in[0];
    const int*   src     = (const int*)d_in[1];
    const int*   dst     = (const int*)d_in[2];
    const int*   gid     = (const int*)d_in[3];
    const float* theta_w = (const float*)d_in[4];
    const float* theta_b = (const float*)d_in[5];
    const float* phi_w   = (const float*)d_in[6];
    const float* phi_b   = (const float*)d_in[7];
    const float* cls_w   = (const float*)d_in[8];
    const float* cls_b   = (const float*)d_in[9];
    float* out = (float*)d_out;

    const size_t NF = (size_t)N_NODES * D;
    char* p = (char*)d_ws;
    bf16_t* t    = (bf16_t*)p;  p += NF * 2;                 // 12.8 MB
    bf16_t* q    = (bf16_t*)p;  p += NF * 2;                 // 12.8 MB
    bf16_t* agg  = (bf16_t*)p;  p += NF * 2;                 // 12.8 MB
    bf16_t* wcat = (bf16_t*)p;  p += 3 * 128 * D * 2;        // 48 KB
    float*  bcat = (float*)p;   p += 3 * D * 4;
    unsigned* bke = (unsigned*)p; p += (size_t)N_EDGES * 4;  // 6.4 MB
    int* bktcnt  = (int*)p;     p += NB * 4;
    int* boff    = (int*)p;     p += (NB + 1) * 4;
    int* gcur    = (int*)p;     p += NB * 4;
    int* hg      = (int*)p;     p += N_GRAPHS * D * 4;
    const size_t need = (size_t)(p - (char*)d_ws);
    if (ws_size < need) {
        hipMemsetAsync(d_out, 0, (size_t)out_size * sizeof(float), stream);
        return;
    }

    const int POOL_GRID = (N_NODES + POOL_NPW * 4 - 1) / (POOL_NPW * 4);  // 782

    // ---- prep: transposed bf16 weights + fused biases ----
    k_prep<<<96, 256, 0, stream>>>(theta_w, phi_w, theta_b, phi_b, wcat, bcat);

    // ---- bucket partition of edges (once; shared by all 3 layers) ----
    k_fill<<<4, 256, 0, stream>>>(bktcnt, NB, 0);
    k_bkt_hist<<<NCHUNK, 256, 0, stream>>>(dst, bktcnt);
    k_bkt_scan<<<1, 256, 0, stream>>>(bktcnt, boff, gcur);
    k_bkt_scatter<<<NCHUNK, 256, 0, stream>>>(src, dst, gcur, bke);

    // ---- 3 EdgeConv layers ----
    k_gemm_mfma<true><<<GEMM_BLOCKS, 256, 0, stream>>>(h, nullptr, wcat, bcat, t, q);
    k_edge_bkt<<<NB, 256, 0, stream>>>(boff, bke, t, q, agg);

    k_gemm_mfma<false><<<GEMM_BLOCKS, 256, 0, stream>>>(
        nullptr, agg, wcat + 128 * D, bcat + D, t, q);
    k_edge_bkt<<<NB, 256, 0, stream>>>(boff, bke, t, q, agg);

    k_gemm_mfma<false><<<GEMM_BLOCKS, 256, 0, stream>>>(
        nullptr, agg, wcat + 2 * 128 * D, bcat + 2 * D, t, q);
    k_edge_bkt<<<NB, 256, 0, stream>>>(boff, bke, t, q, agg);

    // ---- readout ----
    k_fill<<<8, 256, 0, stream>>>(hg, (long)(N_GRAPHS * D), INT_MIN);
    k_pool<<<POOL_GRID, 256, 0, stream>>>(agg, gid, hg);
    k_cls<<<1, 256, 0, stream>>>(hg, cls_w, cls_b, out);
}

// Round 6
// 315.608 us; speedup vs baseline: 2.5113x; 2.5113x over previous
//
#include <hip/hip_runtime.h>
#include <hip/hip_bf16.h>
#include <climits>

#define N_NODES   100000
#define N_EDGES   1600000
#define D         64
#define N_GRAPHS  32
#define N_CLASSES 40
#define N_TILES   (N_NODES / 16)   // 6250 row-tiles of 16
#define TPW       2                // row-tiles per wave
#define GEMM_WAVES ((N_TILES + TPW - 1) / TPW)        // 3125
#define GEMM_BLOCKS ((GEMM_WAVES + 3) / 4)            // 782
#define POOL_NPW  32               // nodes per wave in k_pool

// bucketed edge partition (bucket = 128 consecutive dst nodes)
#define BKT_SHIFT 7
#define BKT_NODES 128
#define NB        ((N_NODES + BKT_NODES - 1) / BKT_NODES)   // 782
#define CHUNK     4096
#define NCHUNK    ((N_EDGES + CHUNK - 1) / CHUNK)           // 391
#define EPT       (CHUNK / 256)                             // 16 edges/thread

typedef __bf16 bf16_t;
typedef bf16_t bf16x8 __attribute__((ext_vector_type(8)));
typedef float  f32x4  __attribute__((ext_vector_type(4)));

// Monotone bijection float -> int (order-preserving for signed int compare).
__device__ __forceinline__ int f2ord(float f) {
    int i = __float_as_int(f);
    return (i >= 0) ? i : (i ^ 0x7FFFFFFF);
}
__device__ __forceinline__ float ord2f(int i) {
    int j = (i >= 0) ? i : (i ^ 0x7FFFFFFF);
    return __int_as_float(j);
}

__global__ __launch_bounds__(256) void k_fill(int* __restrict__ p, long n, int v) {
    long i = (long)blockIdx.x * blockDim.x + threadIdx.x;
    long stride = (long)gridDim.x * blockDim.x;
    for (; i < n; i += stride) p[i] = v;
}

// ---------------- weight prep: wcat[l][n][k] = (n<64 ? tw : pw)[l][k][n%64], bf16 ----------------
__global__ __launch_bounds__(256) void k_prep(
    const float* __restrict__ tw, const float* __restrict__ pw,
    const float* __restrict__ tb, const float* __restrict__ pb,
    bf16_t* __restrict__ wcat, float* __restrict__ bcat)
{
    const int i = blockIdx.x * 256 + threadIdx.x;
    if (i < 3 * 128 * 64) {
        const int l = i >> 13;
        const int rem = i & 8191;
        const int n = rem >> 6;
        const int k = rem & 63;
        const float v = (n < D) ? tw[l * 4096 + k * D + n] : pw[l * 4096 + k * D + (n - D)];
        wcat[i] = (bf16_t)v;
    }
    if (i < 3 * D) bcat[i] = tb[i] + pb[i];
}

// ---------------- CSR build: bucket scatter (write-local) + in-bucket counting sort ----------------

__global__ __launch_bounds__(256) void k_bkt_hist(
    const int* __restrict__ dst, int* __restrict__ bktcnt)
{
    __shared__ int l[NB];
    for (int i = threadIdx.x; i < NB; i += 256) l[i] = 0;
    __syncthreads();
    const int base = blockIdx.x * CHUNK;
    #pragma unroll
    for (int i = 0; i < EPT; ++i) {
        const int e = base + i * 256 + threadIdx.x;
        if (e < N_EDGES) atomicAdd(&l[dst[e] >> BKT_SHIFT], 1);
    }
    __syncthreads();
    for (int i = threadIdx.x; i < NB; i += 256)
        if (l[i]) atomicAdd(&bktcnt[i], l[i]);
}

// Exclusive scan of NB bucket counts (1 block); also inits gcur and boff[NB].
__global__ __launch_bounds__(256) void k_bkt_scan(
    const int* __restrict__ bktcnt, int* __restrict__ boff, int* __restrict__ gcur,
    int* __restrict__ rowptr)
{
    __shared__ int s[256];
    const int t = threadIdx.x;
    int v[4], sum = 0;
    #pragma unroll
    for (int i = 0; i < 4; ++i) {
        const int idx = t * 4 + i;
        v[i] = (idx < NB) ? bktcnt[idx] : 0;
        sum += v[i];
    }
    s[t] = sum;
    __syncthreads();
    #pragma unroll
    for (int off = 1; off < 256; off <<= 1) {
        int x = (t >= off) ? s[t - off] : 0;
        __syncthreads();
        s[t] += x;
        __syncthreads();
    }
    int run = s[t] - sum;
    #pragma unroll
    for (int i = 0; i < 4; ++i) {
        const int idx = t * 4 + i;
        if (idx < NB) {
            boff[idx] = run;
            gcur[idx] = run;
        }
        run += v[i];
    }
    if (t == 255) {
        boff[NB] = N_EDGES;
        rowptr[N_NODES] = N_EDGES;
    }
}

// Pass A: scatter edges into bucket regions. Block-local ranks via LDS, one global
// atomicAdd per (block,bucket) reserves a contiguous run -> write locality.
// Packed edge: (dst & 127) << 17 | src   (src < 2^17).
__global__ __launch_bounds__(256) void k_bkt_scatter(
    const int* __restrict__ src, const int* __restrict__ dst,
    int* __restrict__ gcur, unsigned* __restrict__ bke)
{
    __shared__ int lcnt[NB];
    __shared__ int gb[NB];
    for (int i = threadIdx.x; i < NB; i += 256) lcnt[i] = 0;
    __syncthreads();
    const int base = blockIdx.x * CHUNK;
    unsigned pk[EPT], br[EPT];
    #pragma unroll
    for (int i = 0; i < EPT; ++i) {
        const int e = base + i * 256 + threadIdx.x;
        if (e < N_EDGES) {
            const int d = dst[e];
            const int b = d >> BKT_SHIFT;
            const int r = atomicAdd(&lcnt[b], 1);
            pk[i] = ((unsigned)(d & (BKT_NODES - 1)) << 17) | (unsigned)src[e];
            br[i] = ((unsigned)b << 13) | (unsigned)r;   // r < 4096
        } else {
            br[i] = 0xFFFFFFFFu;
        }
    }
    __syncthreads();
    for (int i = threadIdx.x; i < NB; i += 256) {
        const int c = lcnt[i];
        gb[i] = c ? atomicAdd(&gcur[i], c) : 0;
    }
    __syncthreads();
    #pragma unroll
    for (int i = 0; i < EPT; ++i) {
        if (br[i] != 0xFFFFFFFFu) {
            const int b = br[i] >> 13;
            const int r = br[i] & 8191;
            bke[gb[b] + r] = pk[i];
        }
    }
}

// Pass B: in-bucket counting sort -> per-node CSR order + rowptr.
// One block per bucket; edges land in the bucket's contiguous region of ebuf.
__global__ __launch_bounds__(256) void k_bkt_sort(
    const int* __restrict__ boff, const unsigned* __restrict__ bke,
    int* __restrict__ ebuf, int* __restrict__ rowptr)
{
    __shared__ int cnt[BKT_NODES];   // histogram, then cursor
    __shared__ int pfx[BKT_NODES];   // inclusive scan
    const int b = blockIdx.x;
    const int tid = threadIdx.x;
    const int beg = boff[b];
    const int end = boff[b + 1];

    if (tid < BKT_NODES) cnt[tid] = 0;
    __syncthreads();
    for (int e = beg + tid; e < end; e += 256)
        atomicAdd(&cnt[bke[e] >> 17], 1);
    __syncthreads();
    if (tid < BKT_NODES) pfx[tid] = cnt[tid];
    __syncthreads();
    #pragma unroll
    for (int off = 1; off < BKT_NODES; off <<= 1) {
        int x = 0;
        if (tid < BKT_NODES && tid >= off) x = pfx[tid - off];
        __syncthreads();
        if (tid < BKT_NODES) pfx[tid] += x;
        __syncthreads();
    }
    // exclusive base for local node tid; write rowptr; reset cursor
    if (tid < BKT_NODES) {
        const int excl = pfx[tid] - cnt[tid];
        const int node = b * BKT_NODES + tid;
        if (node <= N_NODES) rowptr[node] = beg + excl;
        cnt[tid] = beg + excl;
    }
    __syncthreads();
    for (int e = beg + tid; e < end; e += 256) {
        const unsigned pk = bke[e];
        const int pos = atomicAdd(&cnt[pk >> 17], 1);
        ebuf[pos] = (int)(pk & 0x1FFFFu);
    }
}

// ---------------- fused node GEMM via MFMA: t = bf16(A@tw), q = bf16(A@pw + b - A@tw) ----------------
template <bool FROM_F32>
__global__ __launch_bounds__(256) void k_gemm_mfma(
    const float* __restrict__ hf, const bf16_t* __restrict__ hb,
    const bf16_t* __restrict__ wcat,  // [128][64] this layer
    const float* __restrict__ bcat,   // [64] this layer
    bf16_t* __restrict__ t, bf16_t* __restrict__ q)
{
    const int lane = threadIdx.x & 63;
    const int wid  = blockIdx.x * 4 + (threadIdx.x >> 6);
    const int r16  = lane & 15;
    const int kg   = lane >> 4;   // 0..3
    const int koff = kg * 8;

    bf16x8 bfrag[8][2];
    #pragma unroll
    for (int c = 0; c < 8; ++c)
        #pragma unroll
        for (int s = 0; s < 2; ++s)
            bfrag[c][s] = *(const bf16x8*)&wcat[(c * 16 + r16) * D + s * 32 + koff];

    float bias[4];
    #pragma unroll
    for (int c = 0; c < 4; ++c) bias[c] = bcat[c * 16 + r16];

    #pragma unroll
    for (int tt = 0; tt < TPW; ++tt) {
        const int tile = wid * TPW + tt;
        if (tile >= N_TILES) return;
        const long rowbase = (long)tile * 16;
        const long arow = rowbase + r16;

        bf16x8 afrag[2];
        if (FROM_F32) {
            #pragma unroll
            for (int s = 0; s < 2; ++s) {
                const f32x4 v0 = *(const f32x4*)&hf[arow * D + s * 32 + koff];
                const f32x4 v1 = *(const f32x4*)&hf[arow * D + s * 32 + koff + 4];
                bf16x8 a;
                a[0] = (bf16_t)v0[0]; a[1] = (bf16_t)v0[1];
                a[2] = (bf16_t)v0[2]; a[3] = (bf16_t)v0[3];
                a[4] = (bf16_t)v1[0]; a[5] = (bf16_t)v1[1];
                a[6] = (bf16_t)v1[2]; a[7] = (bf16_t)v1[3];
                afrag[s] = a;
            }
        } else {
            afrag[0] = *(const bf16x8*)&hb[arow * D + koff];
            afrag[1] = *(const bf16x8*)&hb[arow * D + 32 + koff];
        }

        const f32x4 zero = {0.0f, 0.0f, 0.0f, 0.0f};
        f32x4 acc[8];
        #pragma unroll
        for (int c = 0; c < 8; ++c) {
            acc[c] = __builtin_amdgcn_mfma_f32_16x16x32_bf16(afrag[0], bfrag[c][0], zero, 0, 0, 0);
            acc[c] = __builtin_amdgcn_mfma_f32_16x16x32_bf16(afrag[1], bfrag[c][1], acc[c], 0, 0, 0);
        }

        #pragma unroll
        for (int c = 0; c < 4; ++c) {
            #pragma unroll
            for (int j = 0; j < 4; ++j) {
                const long R = rowbase + kg * 4 + j;
                const int f = c * 16 + r16;
                t[R * D + f] = (bf16_t)acc[c][j];
                q[R * D + f] = (bf16_t)(acc[c + 4][j] - acc[c][j] + bias[c]);
            }
        }
    }
}

// ---------------- gather-max per node (one wave per node, 8 gathers in flight) ----------------
__global__ __launch_bounds__(256) void k_edge_csr(
    const int* __restrict__ rowptr, const int* __restrict__ ebuf,
    const bf16_t* __restrict__ t, const bf16_t* __restrict__ q,
    bf16_t* __restrict__ agg)
{
    const int node = blockIdx.x * 4 + (threadIdx.x >> 6);
    if (node >= N_NODES) return;
    const int lane = threadIdx.x & 63;
    const int beg = rowptr[node];
    const int end = rowptr[node + 1];

    float m = -INFINITY;
    int e = beg;
    for (; e + 7 < end; e += 8) {
        int s[8];
        #pragma unroll
        for (int j = 0; j < 8; ++j) s[j] = ebuf[e + j];
        float v[8];
        #pragma unroll
        for (int j = 0; j < 8; ++j) v[j] = (float)t[(long)s[j] * D + lane];
        #pragma unroll
        for (int j = 0; j < 8; ++j) m = fmaxf(m, v[j]);
    }
    for (; e < end; ++e) {
        const int s0 = ebuf[e];
        m = fmaxf(m, (float)t[(long)s0 * D + lane]);
    }
    const float out = (end > beg) ? m + (float)q[(long)node * D + lane] : 0.0f;
    agg[(long)node * D + lane] = (bf16_t)out;
}

// ---------------- readout ----------------
__global__ __launch_bounds__(256) void k_pool(
    const bf16_t* __restrict__ agg, const int* __restrict__ gid,
    int* __restrict__ hg)
{
    const int lane = threadIdx.x & 63;
    const int wave = threadIdx.x >> 6;
    const int n0 = (blockIdx.x * 4 + wave) * POOL_NPW;
    if (n0 >= N_NODES) return;
    const int nend = (n0 + POOL_NPW < N_NODES) ? n0 + POOL_NPW : N_NODES;
    int cur = gid[n0];
    float m = -INFINITY;
    for (int n = n0; n < nend; ++n) {
        const int g = gid[n];
        if (g != cur) {
            atomicMax(&hg[cur * D + lane], f2ord(m));
            cur = g;
            m = -INFINITY;
        }
        m = fmaxf(m, (float)agg[(long)n * D + lane]);
    }
    atomicMax(&hg[cur * D + lane], f2ord(m));
}

__global__ __launch_bounds__(256) void k_cls(
    const int* __restrict__ hg, const float* __restrict__ w,
    const float* __restrict__ b, float* __restrict__ out)
{
    __shared__ float s_h[N_GRAPHS * D];
    __shared__ float s_w[D * N_CLASSES];
    __shared__ float s_b[N_CLASSES];
    for (int i = threadIdx.x; i < N_GRAPHS * D; i += 256) s_h[i] = ord2f(hg[i]);
    for (int i = threadIdx.x; i < D * N_CLASSES; i += 256) s_w[i] = w[i];
    if (threadIdx.x < N_CLASSES) s_b[threadIdx.x] = b[threadIdx.x];
    __syncthreads();
    for (int o = threadIdx.x; o < N_GRAPHS * N_CLASSES; o += 256) {
        const int g = o / N_CLASSES;
        const int c = o % N_CLASSES;
        float acc = s_b[c];
        #pragma unroll
        for (int k = 0; k < D; ++k)
            acc = fmaf(s_h[g * D + k], s_w[k * N_CLASSES + c], acc);
        out[o] = acc;
    }
}

extern "C" void kernel_launch(void* const* d_in, const int* in_sizes, int n_in,
                              void* d_out, int out_size, void* d_ws, size_t ws_size,
                              hipStream_t stream) {
    const float* h       = (const float*)d_in[0];
    const int*   src     = (const int*)d_in[1];
    const int*   dst     = (const int*)d_in[2];
    const int*   gid     = (const int*)d_in[3];
    const float* theta_w = (const float*)d_in[4];
    const float* theta_b = (const float*)d_in[5];
    const float* phi_w   = (const float*)d_in[6];
    const float* phi_b   = (const float*)d_in[7];
    const float* cls_w   = (const float*)d_in[8];
    const float* cls_b   = (const float*)d_in[9];
    float* out = (float*)d_out;

    const size_t NF = (size_t)N_NODES * D;
    char* p = (char*)d_ws;
    bf16_t* t    = (bf16_t*)p;  p += NF * 2;                 // 12.8 MB
    bf16_t* q    = (bf16_t*)p;  p += NF * 2;                 // 12.8 MB
    bf16_t* agg  = (bf16_t*)p;  p += NF * 2;                 // 12.8 MB
    bf16_t* wcat = (bf16_t*)p;  p += 3 * 128 * D * 2;        // 48 KB
    float*  bcat = (float*)p;   p += 3 * D * 4;
    unsigned* bke = (unsigned*)p; p += (size_t)N_EDGES * 4;  // 6.4 MB
    int* ebuf    = (int*)p;     p += (size_t)N_EDGES * 4;    // 6.4 MB
    int* rowptr  = (int*)p;     p += (N_NODES + 1) * 4;
    int* bktcnt  = (int*)p;     p += NB * 4;
    int* boff    = (int*)p;     p += (NB + 1) * 4;
    int* gcur    = (int*)p;     p += NB * 4;
    int* hg      = (int*)p;     p += N_GRAPHS * D * 4;
    const size_t need = (size_t)(p - (char*)d_ws);
    if (ws_size < need) {
        hipMemsetAsync(d_out, 0, (size_t)out_size * sizeof(float), stream);
        return;
    }

    const int EDGE_GRID = (N_NODES + 3) / 4;
    const int POOL_GRID = (N_NODES + POOL_NPW * 4 - 1) / (POOL_NPW * 4);  // 782

    // ---- prep: transposed bf16 weights + fused biases ----
    k_prep<<<96, 256, 0, stream>>>(theta_w, phi_w, theta_b, phi_b, wcat, bcat);

    // ---- CSR build: bucket scatter + in-bucket counting sort (once; all 3 layers) ----
    k_fill<<<4, 256, 0, stream>>>(bktcnt, NB, 0);
    k_bkt_hist<<<NCHUNK, 256, 0, stream>>>(dst, bktcnt);
    k_bkt_scan<<<1, 256, 0, stream>>>(bktcnt, boff, gcur, rowptr);
    k_bkt_scatter<<<NCHUNK, 256, 0, stream>>>(src, dst, gcur, bke);
    k_bkt_sort<<<NB, 256, 0, stream>>>(boff, bke, ebuf, rowptr);

    // ---- 3 EdgeConv layers ----
    k_gemm_mfma<true><<<GEMM_BLOCKS, 256, 0, stream>>>(h, nullptr, wcat, bcat, t, q);
    k_edge_csr<<<EDGE_GRID, 256, 0, stream>>>(rowptr, ebuf, t, q, agg);

    k_gemm_mfma<false><<<GEMM_BLOCKS, 256, 0, stream>>>(
        nullptr, agg, wcat + 128 * D, bcat + D, t, q);
    k_edge_csr<<<EDGE_GRID, 256, 0, stream>>>(rowptr, ebuf, t, q, agg);

    k_gemm_mfma<false><<<GEMM_BLOCKS, 256, 0, stream>>>(
        nullptr, agg, wcat + 2 * 128 * D, bcat + 2 * D, t, q);
    k_edge_csr<<<EDGE_GRID, 256, 0, stream>>>(rowptr, ebuf, t, q, agg);

    // ---- readout ----
    k_fill<<<8, 256, 0, stream>>>(hg, (long)(N_GRAPHS * D), INT_MIN);
    k_pool<<<POOL_GRID, 256, 0, stream>>>(agg, gid, hg);
    k_cls<<<1, 256, 0, stream>>>(hg, cls_w, cls_b, out);
}

// Round 7
// 299.596 us; speedup vs baseline: 2.6455x; 1.0534x over previous
//
#include <hip/hip_runtime.h>
#include <hip/hip_bf16.h>
#include <climits>

#define N_NODES   100000
#define N_EDGES   1600000
#define D         64
#define N_GRAPHS  32
#define N_CLASSES 40
#define N_TILES   (N_NODES / 16)   // 6250 row-tiles of 16
#define TPW       2                // row-tiles per wave
#define GEMM_WAVES ((N_TILES + TPW - 1) / TPW)        // 3125
#define GEMM_BLOCKS ((GEMM_WAVES + 3) / 4)            // 782
#define POOL_NPW  32               // nodes per wave in k_pool

// bucketed edge partition (bucket = 128 consecutive dst nodes)
#define BKT_SHIFT 7
#define BKT_NODES 128
#define NB        ((N_NODES + BKT_NODES - 1) / BKT_NODES)   // 782
#define CHUNK     4096
#define NCHUNK    ((N_EDGES + CHUNK - 1) / CHUNK)           // 391
#define EPT       (CHUNK / 256)                             // 16 edges/thread

typedef _Float16 f16_t;
typedef f16_t f16x8 __attribute__((ext_vector_type(8)));
typedef float  f32x4  __attribute__((ext_vector_type(4)));

// Monotone bijection float -> int (order-preserving for signed int compare).
__device__ __forceinline__ int f2ord(float f) {
    int i = __float_as_int(f);
    return (i >= 0) ? i : (i ^ 0x7FFFFFFF);
}
__device__ __forceinline__ float ord2f(int i) {
    int j = (i >= 0) ? i : (i ^ 0x7FFFFFFF);
    return __int_as_float(j);
}

__device__ __forceinline__ f16x8 hmax8(f16x8 a, f16x8 b) {
    f16x8 r;
    #pragma unroll
    for (int i = 0; i < 8; ++i) r[i] = (a[i] > b[i]) ? a[i] : b[i];
    return r;
}
__device__ __forceinline__ f16x8 shflxor8(f16x8 v, int mask) {
    union { f16x8 h; int i[4]; } u;
    u.h = v;
    #pragma unroll
    for (int d = 0; d < 4; ++d) u.i[d] = __shfl_xor(u.i[d], mask, 64);
    return u.h;
}

__global__ __launch_bounds__(256) void k_fill(int* __restrict__ p, long n, int v) {
    long i = (long)blockIdx.x * blockDim.x + threadIdx.x;
    long stride = (long)gridDim.x * blockDim.x;
    for (; i < n; i += stride) p[i] = v;
}

// ---------------- weight prep: wcat[l][n][k] = (n<64 ? tw : pw)[l][k][n%64], f16 ----------------
__global__ __launch_bounds__(256) void k_prep(
    const float* __restrict__ tw, const float* __restrict__ pw,
    const float* __restrict__ tb, const float* __restrict__ pb,
    f16_t* __restrict__ wcat, float* __restrict__ bcat)
{
    const int i = blockIdx.x * 256 + threadIdx.x;
    if (i < 3 * 128 * 64) {
        const int l = i >> 13;
        const int rem = i & 8191;
        const int n = rem >> 6;
        const int k = rem & 63;
        const float v = (n < D) ? tw[l * 4096 + k * D + n] : pw[l * 4096 + k * D + (n - D)];
        wcat[i] = (f16_t)v;
    }
    if (i < 3 * D) bcat[i] = tb[i] + pb[i];
}

// ---------------- CSR build: bucket scatter (write-local) + in-bucket counting sort ----------------

__global__ __launch_bounds__(256) void k_bkt_hist(
    const int* __restrict__ dst, int* __restrict__ bktcnt)
{
    __shared__ int l[NB];
    for (int i = threadIdx.x; i < NB; i += 256) l[i] = 0;
    __syncthreads();
    const int base = blockIdx.x * CHUNK;
    #pragma unroll
    for (int i = 0; i < EPT; ++i) {
        const int e = base + i * 256 + threadIdx.x;
        if (e < N_EDGES) atomicAdd(&l[dst[e] >> BKT_SHIFT], 1);
    }
    __syncthreads();
    for (int i = threadIdx.x; i < NB; i += 256)
        if (l[i]) atomicAdd(&bktcnt[i], l[i]);
}

// Exclusive scan of NB bucket counts (1 block); also inits gcur and boff[NB].
__global__ __launch_bounds__(256) void k_bkt_scan(
    const int* __restrict__ bktcnt, int* __restrict__ boff, int* __restrict__ gcur,
    int* __restrict__ rowptr)
{
    __shared__ int s[256];
    const int t = threadIdx.x;
    int v[4], sum = 0;
    #pragma unroll
    for (int i = 0; i < 4; ++i) {
        const int idx = t * 4 + i;
        v[i] = (idx < NB) ? bktcnt[idx] : 0;
        sum += v[i];
    }
    s[t] = sum;
    __syncthreads();
    #pragma unroll
    for (int off = 1; off < 256; off <<= 1) {
        int x = (t >= off) ? s[t - off] : 0;
        __syncthreads();
        s[t] += x;
        __syncthreads();
    }
    int run = s[t] - sum;
    #pragma unroll
    for (int i = 0; i < 4; ++i) {
        const int idx = t * 4 + i;
        if (idx < NB) {
            boff[idx] = run;
            gcur[idx] = run;
        }
        run += v[i];
    }
    if (t == 255) {
        boff[NB] = N_EDGES;
        rowptr[N_NODES] = N_EDGES;
    }
}

// Pass A: scatter edges into bucket regions. Block-local ranks via LDS, one global
// atomicAdd per (block,bucket) reserves a contiguous run -> write locality.
// Packed edge: (dst & 127) << 17 | src   (src < 2^17).
__global__ __launch_bounds__(256) void k_bkt_scatter(
    const int* __restrict__ src, const int* __restrict__ dst,
    int* __restrict__ gcur, unsigned* __restrict__ bke)
{
    __shared__ int lcnt[NB];
    __shared__ int gb[NB];
    for (int i = threadIdx.x; i < NB; i += 256) lcnt[i] = 0;
    __syncthreads();
    const int base = blockIdx.x * CHUNK;
    unsigned pk[EPT], br[EPT];
    #pragma unroll
    for (int i = 0; i < EPT; ++i) {
        const int e = base + i * 256 + threadIdx.x;
        if (e < N_EDGES) {
            const int d = dst[e];
            const int b = d >> BKT_SHIFT;
            const int r = atomicAdd(&lcnt[b], 1);
            pk[i] = ((unsigned)(d & (BKT_NODES - 1)) << 17) | (unsigned)src[e];
            br[i] = ((unsigned)b << 13) | (unsigned)r;   // r < 4096
        } else {
            br[i] = 0xFFFFFFFFu;
        }
    }
    __syncthreads();
    for (int i = threadIdx.x; i < NB; i += 256) {
        const int c = lcnt[i];
        gb[i] = c ? atomicAdd(&gcur[i], c) : 0;
    }
    __syncthreads();
    #pragma unroll
    for (int i = 0; i < EPT; ++i) {
        if (br[i] != 0xFFFFFFFFu) {
            const int b = br[i] >> 13;
            const int r = br[i] & 8191;
            bke[gb[b] + r] = pk[i];
        }
    }
}

// Pass B: in-bucket counting sort -> per-node CSR order + rowptr.
__global__ __launch_bounds__(256) void k_bkt_sort(
    const int* __restrict__ boff, const unsigned* __restrict__ bke,
    int* __restrict__ ebuf, int* __restrict__ rowptr)
{
    __shared__ int cnt[BKT_NODES];   // histogram, then cursor
    __shared__ int pfx[BKT_NODES];   // inclusive scan
    const int b = blockIdx.x;
    const int tid = threadIdx.x;
    const int beg = boff[b];
    const int end = boff[b + 1];

    if (tid < BKT_NODES) cnt[tid] = 0;
    __syncthreads();
    for (int e = beg + tid; e < end; e += 256)
        atomicAdd(&cnt[bke[e] >> 17], 1);
    __syncthreads();
    if (tid < BKT_NODES) pfx[tid] = cnt[tid];
    __syncthreads();
    #pragma unroll
    for (int off = 1; off < BKT_NODES; off <<= 1) {
        int x = 0;
        if (tid < BKT_NODES && tid >= off) x = pfx[tid - off];
        __syncthreads();
        if (tid < BKT_NODES) pfx[tid] += x;
        __syncthreads();
    }
    if (tid < BKT_NODES) {
        const int excl = pfx[tid] - cnt[tid];
        const int node = b * BKT_NODES + tid;
        if (node <= N_NODES) rowptr[node] = beg + excl;
        cnt[tid] = beg + excl;
    }
    __syncthreads();
    for (int e = beg + tid; e < end; e += 256) {
        const unsigned pk = bke[e];
        const int pos = atomicAdd(&cnt[pk >> 17], 1);
        ebuf[pos] = (int)(pk & 0x1FFFFu);
    }
}

// ---------------- fused node GEMM via MFMA (f16): t = A@tw, q = A@pw + b - A@tw ----------------
template <bool FROM_F32>
__global__ __launch_bounds__(256) void k_gemm_mfma(
    const float* __restrict__ hf, const f16_t* __restrict__ hb,
    const f16_t* __restrict__ wcat,  // [128][64] this layer
    const float* __restrict__ bcat,  // [64] this layer
    f16_t* __restrict__ t, f16_t* __restrict__ q)
{
    const int lane = threadIdx.x & 63;
    const int wid  = blockIdx.x * 4 + (threadIdx.x >> 6);
    const int r16  = lane & 15;
    const int kg   = lane >> 4;   // 0..3
    const int koff = kg * 8;

    f16x8 bfrag[8][2];
    #pragma unroll
    for (int c = 0; c < 8; ++c)
        #pragma unroll
        for (int s = 0; s < 2; ++s)
            bfrag[c][s] = *(const f16x8*)&wcat[(c * 16 + r16) * D + s * 32 + koff];

    float bias[4];
    #pragma unroll
    for (int c = 0; c < 4; ++c) bias[c] = bcat[c * 16 + r16];

    #pragma unroll
    for (int tt = 0; tt < TPW; ++tt) {
        const int tile = wid * TPW + tt;
        if (tile >= N_TILES) return;
        const long rowbase = (long)tile * 16;
        const long arow = rowbase + r16;

        f16x8 afrag[2];
        if (FROM_F32) {
            #pragma unroll
            for (int s = 0; s < 2; ++s) {
                const f32x4 v0 = *(const f32x4*)&hf[arow * D + s * 32 + koff];
                const f32x4 v1 = *(const f32x4*)&hf[arow * D + s * 32 + koff + 4];
                f16x8 a;
                a[0] = (f16_t)v0[0]; a[1] = (f16_t)v0[1];
                a[2] = (f16_t)v0[2]; a[3] = (f16_t)v0[3];
                a[4] = (f16_t)v1[0]; a[5] = (f16_t)v1[1];
                a[6] = (f16_t)v1[2]; a[7] = (f16_t)v1[3];
                afrag[s] = a;
            }
        } else {
            afrag[0] = *(const f16x8*)&hb[arow * D + koff];
            afrag[1] = *(const f16x8*)&hb[arow * D + 32 + koff];
        }

        const f32x4 zero = {0.0f, 0.0f, 0.0f, 0.0f};
        f32x4 acc[8];
        #pragma unroll
        for (int c = 0; c < 8; ++c) {
            acc[c] = __builtin_amdgcn_mfma_f32_16x16x32_f16(afrag[0], bfrag[c][0], zero, 0, 0, 0);
            acc[c] = __builtin_amdgcn_mfma_f32_16x16x32_f16(afrag[1], bfrag[c][1], acc[c], 0, 0, 0);
        }

        #pragma unroll
        for (int c = 0; c < 4; ++c) {
            #pragma unroll
            for (int j = 0; j < 4; ++j) {
                const long R = rowbase + kg * 4 + j;
                const int f = c * 16 + r16;
                t[R * D + f] = (f16_t)acc[c][j];
                q[R * D + f] = (f16_t)(acc[c + 4][j] - acc[c][j] + bias[c]);
            }
        }
    }
}

// ---------------- gather-max per node: lane = j*8+g, 16 B/lane loads ----------------
// One wave per node. Per 8-edge group one dwordx4 load covers all 64 features of 8 rows.
__global__ __launch_bounds__(256) void k_edge_csr(
    const int* __restrict__ rowptr, const int* __restrict__ ebuf,
    const f16_t* __restrict__ t, const f16_t* __restrict__ q,
    f16_t* __restrict__ agg)
{
    const int node = blockIdx.x * 4 + (threadIdx.x >> 6);
    if (node >= N_NODES) return;
    const int lane = threadIdx.x & 63;
    const int j = lane >> 3;      // edge sub-index 0..7
    const int g = lane & 7;       // feature group (features g*8..g*8+7)
    const int beg = rowptr[node];
    const int end = rowptr[node + 1];

    f16x8 neg8;
    #pragma unroll
    for (int i = 0; i < 8; ++i) neg8[i] = (f16_t)(-65504.0f);

    f16x8 m0 = neg8, m1 = neg8;
    for (int e0 = beg; e0 < end; e0 += 16) {
        const int ea = e0 + j;
        const int eb = e0 + 8 + j;
        f16x8 va = neg8, vb = neg8;
        if (ea < end) va = *(const f16x8*)&t[(long)ebuf[ea] * D + g * 8];
        if (eb < end) vb = *(const f16x8*)&t[(long)ebuf[eb] * D + g * 8];
        m0 = hmax8(m0, va);
        m1 = hmax8(m1, vb);
    }
    f16x8 m = hmax8(m0, m1);
    m = hmax8(m, shflxor8(m, 8));
    m = hmax8(m, shflxor8(m, 16));
    m = hmax8(m, shflxor8(m, 32));

    if (j == 0) {  // lanes 0..7 write the 128 B agg row coalesced
        const f16x8 qv = *(const f16x8*)&q[(long)node * D + g * 8];
        f16x8 o;
        if (end > beg) {
            #pragma unroll
            for (int i = 0; i < 8; ++i)
                o[i] = (f16_t)((float)m[i] + (float)qv[i]);
        } else {
            #pragma unroll
            for (int i = 0; i < 8; ++i) o[i] = (f16_t)0.0f;
        }
        *(f16x8*)&agg[(long)node * D + g * 8] = o;
    }
}

// ---------------- readout ----------------
__global__ __launch_bounds__(256) void k_pool(
    const f16_t* __restrict__ agg, const int* __restrict__ gid,
    int* __restrict__ hg)
{
    const int lane = threadIdx.x & 63;
    const int wave = threadIdx.x >> 6;
    const int n0 = (blockIdx.x * 4 + wave) * POOL_NPW;
    if (n0 >= N_NODES) return;
    const int nend = (n0 + POOL_NPW < N_NODES) ? n0 + POOL_NPW : N_NODES;
    int cur = gid[n0];
    float m = -INFINITY;
    for (int n = n0; n < nend; ++n) {
        const int g = gid[n];
        if (g != cur) {
            atomicMax(&hg[cur * D + lane], f2ord(m));
            cur = g;
            m = -INFINITY;
        }
        m = fmaxf(m, (float)agg[(long)n * D + lane]);
    }
    atomicMax(&hg[cur * D + lane], f2ord(m));
}

__global__ __launch_bounds__(256) void k_cls(
    const int* __restrict__ hg, const float* __restrict__ w,
    const float* __restrict__ b, float* __restrict__ out)
{
    __shared__ float s_h[N_GRAPHS * D];
    __shared__ float s_w[D * N_CLASSES];
    __shared__ float s_b[N_CLASSES];
    for (int i = threadIdx.x; i < N_GRAPHS * D; i += 256) s_h[i] = ord2f(hg[i]);
    for (int i = threadIdx.x; i < D * N_CLASSES; i += 256) s_w[i] = w[i];
    if (threadIdx.x < N_CLASSES) s_b[threadIdx.x] = b[threadIdx.x];
    __syncthreads();
    for (int o = threadIdx.x; o < N_GRAPHS * N_CLASSES; o += 256) {
        const int g = o / N_CLASSES;
        const int c = o % N_CLASSES;
        float acc = s_b[c];
        #pragma unroll
        for (int k = 0; k < D; ++k)
            acc = fmaf(s_h[g * D + k], s_w[k * N_CLASSES + c], acc);
        out[o] = acc;
    }
}

extern "C" void kernel_launch(void* const* d_in, const int* in_sizes, int n_in,
                              void* d_out, int out_size, void* d_ws, size_t ws_size,
                              hipStream_t stream) {
    const float* h       = (const float*)d_in[0];
    const int*   src     = (const int*)d_in[1];
    const int*   dst     = (const int*)d_in[2];
    const int*   gid     = (const int*)d_in[3];
    const float* theta_w = (const float*)d_in[4];
    const float* theta_b = (const float*)d_in[5];
    const float* phi_w   = (const float*)d_in[6];
    const float* phi_b   = (const float*)d_in[7];
    const float* cls_w   = (const float*)d_in[8];
    const float* cls_b   = (const float*)d_in[9];
    float* out = (float*)d_out;

    const size_t NF = (size_t)N_NODES * D;
    char* p = (char*)d_ws;
    f16_t* t     = (f16_t*)p;   p += NF * 2;                 // 12.8 MB
    f16_t* q     = (f16_t*)p;   p += NF * 2;                 // 12.8 MB
    f16_t* agg   = (f16_t*)p;   p += NF * 2;                 // 12.8 MB
    f16_t* wcat  = (f16_t*)p;   p += 3 * 128 * D * 2;        // 48 KB
    float*  bcat = (float*)p;   p += 3 * D * 4;
    unsigned* bke = (unsigned*)p; p += (size_t)N_EDGES * 4;  // 6.4 MB
    int* ebuf    = (int*)p;     p += (size_t)N_EDGES * 4;    // 6.4 MB
    int* rowptr  = (int*)p;     p += (N_NODES + 1) * 4;
    int* bktcnt  = (int*)p;     p += NB * 4;
    int* boff    = (int*)p;     p += (NB + 1) * 4;
    int* gcur    = (int*)p;     p += NB * 4;
    int* hg      = (int*)p;     p += N_GRAPHS * D * 4;
    const size_t need = (size_t)(p - (char*)d_ws);
    if (ws_size < need) {
        hipMemsetAsync(d_out, 0, (size_t)out_size * sizeof(float), stream);
        return;
    }

    const int EDGE_GRID = (N_NODES + 3) / 4;
    const int POOL_GRID = (N_NODES + POOL_NPW * 4 - 1) / (POOL_NPW * 4);  // 782

    // ---- prep: transposed f16 weights + fused biases ----
    k_prep<<<96, 256, 0, stream>>>(theta_w, phi_w, theta_b, phi_b, wcat, bcat);

    // ---- CSR build: bucket scatter + in-bucket counting sort (once; all 3 layers) ----
    k_fill<<<4, 256, 0, stream>>>(bktcnt, NB, 0);
    k_bkt_hist<<<NCHUNK, 256, 0, stream>>>(dst, bktcnt);
    k_bkt_scan<<<1, 256, 0, stream>>>(bktcnt, boff, gcur, rowptr);
    k_bkt_scatter<<<NCHUNK, 256, 0, stream>>>(src, dst, gcur, bke);
    k_bkt_sort<<<NB, 256, 0, stream>>>(boff, bke, ebuf, rowptr);

    // ---- 3 EdgeConv layers ----
    k_gemm_mfma<true><<<GEMM_BLOCKS, 256, 0, stream>>>(h, nullptr, wcat, bcat, t, q);
    k_edge_csr<<<EDGE_GRID, 256, 0, stream>>>(rowptr, ebuf, t, q, agg);

    k_gemm_mfma<false><<<GEMM_BLOCKS, 256, 0, stream>>>(
        nullptr, agg, wcat + 128 * D, bcat + D, t, q);
    k_edge_csr<<<EDGE_GRID, 256, 0, stream>>>(rowptr, ebuf, t, q, agg);

    k_gemm_mfma<false><<<GEMM_BLOCKS, 256, 0, stream>>>(
        nullptr, agg, wcat + 2 * 128 * D, bcat + 2 * D, t, q);
    k_edge_csr<<<EDGE_GRID, 256, 0, stream>>>(rowptr, ebuf, t, q, agg);

    // ---- readout ----
    k_fill<<<8, 256, 0, stream>>>(hg, (long)(N_GRAPHS * D), INT_MIN);
    k_pool<<<POOL_GRID, 256, 0, stream>>>(agg, gid, hg);
    k_cls<<<1, 256, 0, stream>>>(hg, cls_w, cls_b, out);
}

// Round 8
// 254.555 us; speedup vs baseline: 3.1136x; 1.1769x over previous
//
#include <hip/hip_runtime.h>
#include <hip/hip_bf16.h>
#include <climits>

#define N_NODES   100000
#define N_EDGES   1600000
#define D         64
#define N_GRAPHS  32
#define N_CLASSES 40
#define N_TILES   (N_NODES / 16)   // 6250 row-tiles of 16
#define TPW       2                // row-tiles per wave
#define GEMM_WAVES ((N_TILES + TPW - 1) / TPW)        // 3125
#define GEMM_BLOCKS ((GEMM_WAVES + 3) / 4)            // 782
#define POOL_NPW  32               // nodes per wave in k_pool

// bucketed edge partition (bucket = 128 consecutive dst nodes)
#define BKT_SHIFT 7
#define BKT_NODES 128
#define NB        ((N_NODES + BKT_NODES - 1) / BKT_NODES)   // 782
#define CHUNK     4096
#define NCHUNK    ((N_EDGES + CHUNK - 1) / CHUNK)           // 391
#define EPT       (CHUNK / 256)                             // 16 edges/thread

typedef _Float16 f16_t;
typedef f16_t f16x8 __attribute__((ext_vector_type(8)));
typedef float  f32x4  __attribute__((ext_vector_type(4)));

// Monotone bijection float -> int (order-preserving for signed int compare).
__device__ __forceinline__ int f2ord(float f) {
    int i = __float_as_int(f);
    return (i >= 0) ? i : (i ^ 0x7FFFFFFF);
}
__device__ __forceinline__ float ord2f(int i) {
    int j = (i >= 0) ? i : (i ^ 0x7FFFFFFF);
    return __int_as_float(j);
}

__device__ __forceinline__ f16x8 shflxor8(f16x8 v, int mask) {
    union { f16x8 h; int i[4]; } u;
    u.h = v;
    #pragma unroll
    for (int d = 0; d < 4; ++d) u.i[d] = __shfl_xor(u.i[d], mask, 64);
    return u.h;
}

__global__ __launch_bounds__(256) void k_fill(int* __restrict__ p, long n, int v) {
    long i = (long)blockIdx.x * blockDim.x + threadIdx.x;
    long stride = (long)gridDim.x * blockDim.x;
    for (; i < n; i += stride) p[i] = v;
}

// ---------------- weight prep: wcat[l][n][k] = (n<64 ? tw : pw)[l][k][n%64], f16 ----------------
__global__ __launch_bounds__(256) void k_prep(
    const float* __restrict__ tw, const float* __restrict__ pw,
    const float* __restrict__ tb, const float* __restrict__ pb,
    f16_t* __restrict__ wcat, float* __restrict__ bcat)
{
    const int i = blockIdx.x * 256 + threadIdx.x;
    if (i < 3 * 128 * 64) {
        const int l = i >> 13;
        const int rem = i & 8191;
        const int n = rem >> 6;
        const int k = rem & 63;
        const float v = (n < D) ? tw[l * 4096 + k * D + n] : pw[l * 4096 + k * D + (n - D)];
        wcat[i] = (f16_t)v;
    }
    if (i < 3 * D) bcat[i] = tb[i] + pb[i];
}

// ---------------- CSR build: bucket scatter (write-local) + in-bucket counting sort ----------------

__global__ __launch_bounds__(256) void k_bkt_hist(
    const int* __restrict__ dst, int* __restrict__ bktcnt)
{
    __shared__ int l[NB];
    for (int i = threadIdx.x; i < NB; i += 256) l[i] = 0;
    __syncthreads();
    const int base = blockIdx.x * CHUNK;
    #pragma unroll
    for (int i = 0; i < EPT; ++i) {
        const int e = base + i * 256 + threadIdx.x;
        if (e < N_EDGES) atomicAdd(&l[dst[e] >> BKT_SHIFT], 1);
    }
    __syncthreads();
    for (int i = threadIdx.x; i < NB; i += 256)
        if (l[i]) atomicAdd(&bktcnt[i], l[i]);
}

// Exclusive scan of NB bucket counts (1 block); also inits gcur and boff[NB].
__global__ __launch_bounds__(256) void k_bkt_scan(
    const int* __restrict__ bktcnt, int* __restrict__ boff, int* __restrict__ gcur,
    int* __restrict__ rowptr)
{
    __shared__ int s[256];
    const int t = threadIdx.x;
    int v[4], sum = 0;
    #pragma unroll
    for (int i = 0; i < 4; ++i) {
        const int idx = t * 4 + i;
        v[i] = (idx < NB) ? bktcnt[idx] : 0;
        sum += v[i];
    }
    s[t] = sum;
    __syncthreads();
    #pragma unroll
    for (int off = 1; off < 256; off <<= 1) {
        int x = (t >= off) ? s[t - off] : 0;
        __syncthreads();
        s[t] += x;
        __syncthreads();
    }
    int run = s[t] - sum;
    #pragma unroll
    for (int i = 0; i < 4; ++i) {
        const int idx = t * 4 + i;
        if (idx < NB) {
            boff[idx] = run;
            gcur[idx] = run;
        }
        run += v[i];
    }
    if (t == 255) {
        boff[NB] = N_EDGES;
        rowptr[N_NODES] = N_EDGES;
    }
}

// Pass A: scatter edges into bucket regions. Block-local ranks via LDS, one global
// atomicAdd per (block,bucket) reserves a contiguous run -> write locality.
// Packed edge: (dst & 127) << 17 | src   (src < 2^17).
__global__ __launch_bounds__(256) void k_bkt_scatter(
    const int* __restrict__ src, const int* __restrict__ dst,
    int* __restrict__ gcur, unsigned* __restrict__ bke)
{
    __shared__ int lcnt[NB];
    __shared__ int gb[NB];
    for (int i = threadIdx.x; i < NB; i += 256) lcnt[i] = 0;
    __syncthreads();
    const int base = blockIdx.x * CHUNK;
    unsigned pk[EPT], br[EPT];
    #pragma unroll
    for (int i = 0; i < EPT; ++i) {
        const int e = base + i * 256 + threadIdx.x;
        if (e < N_EDGES) {
            const int d = dst[e];
            const int b = d >> BKT_SHIFT;
            const int r = atomicAdd(&lcnt[b], 1);
            pk[i] = ((unsigned)(d & (BKT_NODES - 1)) << 17) | (unsigned)src[e];
            br[i] = ((unsigned)b << 13) | (unsigned)r;   // r < 4096
        } else {
            br[i] = 0xFFFFFFFFu;
        }
    }
    __syncthreads();
    for (int i = threadIdx.x; i < NB; i += 256) {
        const int c = lcnt[i];
        gb[i] = c ? atomicAdd(&gcur[i], c) : 0;
    }
    __syncthreads();
    #pragma unroll
    for (int i = 0; i < EPT; ++i) {
        if (br[i] != 0xFFFFFFFFu) {
            const int b = br[i] >> 13;
            const int r = br[i] & 8191;
            bke[gb[b] + r] = pk[i];
        }
    }
}

// Pass B: in-bucket counting sort -> per-node CSR order + rowptr.
__global__ __launch_bounds__(256) void k_bkt_sort(
    const int* __restrict__ boff, const unsigned* __restrict__ bke,
    int* __restrict__ ebuf, int* __restrict__ rowptr)
{
    __shared__ int cnt[BKT_NODES];   // histogram, then cursor
    __shared__ int pfx[BKT_NODES];   // inclusive scan
    const int b = blockIdx.x;
    const int tid = threadIdx.x;
    const int beg = boff[b];
    const int end = boff[b + 1];

    if (tid < BKT_NODES) cnt[tid] = 0;
    __syncthreads();
    for (int e = beg + tid; e < end; e += 256)
        atomicAdd(&cnt[bke[e] >> 17], 1);
    __syncthreads();
    if (tid < BKT_NODES) pfx[tid] = cnt[tid];
    __syncthreads();
    #pragma unroll
    for (int off = 1; off < BKT_NODES; off <<= 1) {
        int x = 0;
        if (tid < BKT_NODES && tid >= off) x = pfx[tid - off];
        __syncthreads();
        if (tid < BKT_NODES) pfx[tid] += x;
        __syncthreads();
    }
    if (tid < BKT_NODES) {
        const int excl = pfx[tid] - cnt[tid];
        const int node = b * BKT_NODES + tid;
        if (node <= N_NODES) rowptr[node] = beg + excl;
        cnt[tid] = beg + excl;
    }
    __syncthreads();
    for (int e = beg + tid; e < end; e += 256) {
        const unsigned pk = bke[e];
        const int pos = atomicAdd(&cnt[pk >> 17], 1);
        ebuf[pos] = (int)(pk & 0x1FFFFu);
    }
}

// ---------------- fused node GEMM via MFMA (f16): t = A@tw, q = A@pw + b - A@tw ----------------
template <bool FROM_F32>
__global__ __launch_bounds__(256) void k_gemm_mfma(
    const float* __restrict__ hf, const f16_t* __restrict__ hb,
    const f16_t* __restrict__ wcat,  // [128][64] this layer
    const float* __restrict__ bcat,  // [64] this layer
    f16_t* __restrict__ t, f16_t* __restrict__ q)
{
    const int lane = threadIdx.x & 63;
    const int wid  = blockIdx.x * 4 + (threadIdx.x >> 6);
    const int r16  = lane & 15;
    const int kg   = lane >> 4;   // 0..3
    const int koff = kg * 8;

    f16x8 bfrag[8][2];
    #pragma unroll
    for (int c = 0; c < 8; ++c)
        #pragma unroll
        for (int s = 0; s < 2; ++s)
            bfrag[c][s] = *(const f16x8*)&wcat[(c * 16 + r16) * D + s * 32 + koff];

    float bias[4];
    #pragma unroll
    for (int c = 0; c < 4; ++c) bias[c] = bcat[c * 16 + r16];

    #pragma unroll
    for (int tt = 0; tt < TPW; ++tt) {
        const int tile = wid * TPW + tt;
        if (tile >= N_TILES) return;
        const long rowbase = (long)tile * 16;
        const long arow = rowbase + r16;

        f16x8 afrag[2];
        if (FROM_F32) {
            #pragma unroll
            for (int s = 0; s < 2; ++s) {
                const f32x4 v0 = *(const f32x4*)&hf[arow * D + s * 32 + koff];
                const f32x4 v1 = *(const f32x4*)&hf[arow * D + s * 32 + koff + 4];
                f16x8 a;
                a[0] = (f16_t)v0[0]; a[1] = (f16_t)v0[1];
                a[2] = (f16_t)v0[2]; a[3] = (f16_t)v0[3];
                a[4] = (f16_t)v1[0]; a[5] = (f16_t)v1[1];
                a[6] = (f16_t)v1[2]; a[7] = (f16_t)v1[3];
                afrag[s] = a;
            }
        } else {
            afrag[0] = *(const f16x8*)&hb[arow * D + koff];
            afrag[1] = *(const f16x8*)&hb[arow * D + 32 + koff];
        }

        const f32x4 zero = {0.0f, 0.0f, 0.0f, 0.0f};
        f32x4 acc[8];
        #pragma unroll
        for (int c = 0; c < 8; ++c) {
            acc[c] = __builtin_amdgcn_mfma_f32_16x16x32_f16(afrag[0], bfrag[c][0], zero, 0, 0, 0);
            acc[c] = __builtin_amdgcn_mfma_f32_16x16x32_f16(afrag[1], bfrag[c][1], acc[c], 0, 0, 0);
        }

        #pragma unroll
        for (int c = 0; c < 4; ++c) {
            #pragma unroll
            for (int j = 0; j < 4; ++j) {
                const long R = rowbase + kg * 4 + j;
                const int f = c * 16 + r16;
                t[R * D + f] = (f16_t)acc[c][j];
                q[R * D + f] = (f16_t)(acc[c + 4][j] - acc[c][j] + bias[c]);
            }
        }
    }
}

// ---------------- gather-max per node: lane = j*8+g, 16 B/lane loads ----------------
// One wave per node. Duplicate-row loads via index clamping are idempotent under max,
// so the tail needs no predication. Packed f16 max via __builtin_elementwise_max.
__global__ __launch_bounds__(256) void k_edge_csr(
    const int* __restrict__ rowptr, const int* __restrict__ ebuf,
    const f16_t* __restrict__ t, const f16_t* __restrict__ q,
    f16_t* __restrict__ agg)
{
    const int node = blockIdx.x * 4 + (threadIdx.x >> 6);
    if (node >= N_NODES) return;
    const int lane = threadIdx.x & 63;
    const int j = lane >> 3;      // edge sub-index 0..7
    const int g = lane & 7;       // feature group (features g*8..g*8+7)
    const int beg = rowptr[node];
    const int end = rowptr[node + 1];

    if (end == beg) {             // no in-edges: DGL zero-fill
        if (j == 0) {
            f16x8 z;
            #pragma unroll
            for (int i = 0; i < 8; ++i) z[i] = (f16_t)0.0f;
            *(f16x8*)&agg[(long)node * D + g * 8] = z;
        }
        return;
    }

    const int last = end - 1;
    const int go = g * 8;
    // first 16 edges seed the accumulators (clamped; duplicates are no-ops under max)
    f16x8 m0 = *(const f16x8*)&t[((long)ebuf[min(beg + j,     last)] << 6) + go];
    f16x8 m1 = *(const f16x8*)&t[((long)ebuf[min(beg + 8 + j, last)] << 6) + go];
    for (int e0 = beg + 16; e0 < end; e0 += 16) {
        const int ra = ebuf[min(e0 + j,     last)];
        const int rb = ebuf[min(e0 + 8 + j, last)];
        const f16x8 va = *(const f16x8*)&t[((long)ra << 6) + go];
        const f16x8 vb = *(const f16x8*)&t[((long)rb << 6) + go];
        m0 = __builtin_elementwise_max(m0, va);
        m1 = __builtin_elementwise_max(m1, vb);
    }
    f16x8 m = __builtin_elementwise_max(m0, m1);
    m = __builtin_elementwise_max(m, shflxor8(m, 8));
    m = __builtin_elementwise_max(m, shflxor8(m, 16));
    m = __builtin_elementwise_max(m, shflxor8(m, 32));

    if (j == 0) {  // lanes 0..7 write the 128 B agg row coalesced
        const f16x8 qv = *(const f16x8*)&q[(long)node * D + go];
        *(f16x8*)&agg[(long)node * D + go] = m + qv;
    }
}

// ---------------- readout ----------------
__global__ __launch_bounds__(256) void k_pool(
    const f16_t* __restrict__ agg, const int* __restrict__ gid,
    int* __restrict__ hg)
{
    const int lane = threadIdx.x & 63;
    const int wave = threadIdx.x >> 6;
    const int n0 = (blockIdx.x * 4 + wave) * POOL_NPW;
    if (n0 >= N_NODES) return;
    const int nend = (n0 + POOL_NPW < N_NODES) ? n0 + POOL_NPW : N_NODES;
    int cur = gid[n0];
    float m = -INFINITY;
    for (int n = n0; n < nend; ++n) {
        const int g = gid[n];
        if (g != cur) {
            atomicMax(&hg[cur * D + lane], f2ord(m));
            cur = g;
            m = -INFINITY;
        }
        m = fmaxf(m, (float)agg[(long)n * D + lane]);
    }
    atomicMax(&hg[cur * D + lane], f2ord(m));
}

__global__ __launch_bounds__(256) void k_cls(
    const int* __restrict__ hg, const float* __restrict__ w,
    const float* __restrict__ b, float* __restrict__ out)
{
    __shared__ float s_h[N_GRAPHS * D];
    __shared__ float s_w[D * N_CLASSES];
    __shared__ float s_b[N_CLASSES];
    for (int i = threadIdx.x; i < N_GRAPHS * D; i += 256) s_h[i] = ord2f(hg[i]);
    for (int i = threadIdx.x; i < D * N_CLASSES; i += 256) s_w[i] = w[i];
    if (threadIdx.x < N_CLASSES) s_b[threadIdx.x] = b[threadIdx.x];
    __syncthreads();
    for (int o = threadIdx.x; o < N_GRAPHS * N_CLASSES; o += 256) {
        const int g = o / N_CLASSES;
        const int c = o % N_CLASSES;
        float acc = s_b[c];
        #pragma unroll
        for (int k = 0; k < D; ++k)
            acc = fmaf(s_h[g * D + k], s_w[k * N_CLASSES + c], acc);
        out[o] = acc;
    }
}

extern "C" void kernel_launch(void* const* d_in, const int* in_sizes, int n_in,
                              void* d_out, int out_size, void* d_ws, size_t ws_size,
                              hipStream_t stream) {
    const float* h       = (const float*)d_in[0];
    const int*   src     = (const int*)d_in[1];
    const int*   dst     = (const int*)d_in[2];
    const int*   gid     = (const int*)d_in[3];
    const float* theta_w = (const float*)d_in[4];
    const float* theta_b = (const float*)d_in[5];
    const float* phi_w   = (const float*)d_in[6];
    const float* phi_b   = (const float*)d_in[7];
    const float* cls_w   = (const float*)d_in[8];
    const float* cls_b   = (const float*)d_in[9];
    float* out = (float*)d_out;

    const size_t NF = (size_t)N_NODES * D;
    char* p = (char*)d_ws;
    f16_t* t     = (f16_t*)p;   p += NF * 2;                 // 12.8 MB
    f16_t* q     = (f16_t*)p;   p += NF * 2;                 // 12.8 MB
    f16_t* agg   = (f16_t*)p;   p += NF * 2;                 // 12.8 MB
    f16_t* wcat  = (f16_t*)p;   p += 3 * 128 * D * 2;        // 48 KB
    float*  bcat = (float*)p;   p += 3 * D * 4;
    unsigned* bke = (unsigned*)p; p += (size_t)N_EDGES * 4;  // 6.4 MB
    int* ebuf    = (int*)p;     p += (size_t)N_EDGES * 4;    // 6.4 MB
    int* rowptr  = (int*)p;     p += (N_NODES + 1) * 4;
    int* bktcnt  = (int*)p;     p += NB * 4;
    int* boff    = (int*)p;     p += (NB + 1) * 4;
    int* gcur    = (int*)p;     p += NB * 4;
    int* hg      = (int*)p;     p += N_GRAPHS * D * 4;
    const size_t need = (size_t)(p - (char*)d_ws);
    if (ws_size < need) {
        hipMemsetAsync(d_out, 0, (size_t)out_size * sizeof(float), stream);
        return;
    }

    const int EDGE_GRID = (N_NODES + 3) / 4;
    const int POOL_GRID = (N_NODES + POOL_NPW * 4 - 1) / (POOL_NPW * 4);  // 782

    // ---- prep: transposed f16 weights + fused biases ----
    k_prep<<<96, 256, 0, stream>>>(theta_w, phi_w, theta_b, phi_b, wcat, bcat);

    // ---- CSR build: bucket scatter + in-bucket counting sort (once; all 3 layers) ----
    k_fill<<<4, 256, 0, stream>>>(bktcnt, NB, 0);
    k_bkt_hist<<<NCHUNK, 256, 0, stream>>>(dst, bktcnt);
    k_bkt_scan<<<1, 256, 0, stream>>>(bktcnt, boff, gcur, rowptr);
    k_bkt_scatter<<<NCHUNK, 256, 0, stream>>>(src, dst, gcur, bke);
    k_bkt_sort<<<NB, 256, 0, stream>>>(boff, bke, ebuf, rowptr);

    // ---- 3 EdgeConv layers ----
    k_gemm_mfma<true><<<GEMM_BLOCKS, 256, 0, stream>>>(h, nullptr, wcat, bcat, t, q);
    k_edge_csr<<<EDGE_GRID, 256, 0, stream>>>(rowptr, ebuf, t, q, agg);

    k_gemm_mfma<false><<<GEMM_BLOCKS, 256, 0, stream>>>(
        nullptr, agg, wcat + 128 * D, bcat + D, t, q);
    k_edge_csr<<<EDGE_GRID, 256, 0, stream>>>(rowptr, ebuf, t, q, agg);

    k_gemm_mfma<false><<<GEMM_BLOCKS, 256, 0, stream>>>(
        nullptr, agg, wcat + 2 * 128 * D, bcat + 2 * D, t, q);
    k_edge_csr<<<EDGE_GRID, 256, 0, stream>>>(rowptr, ebuf, t, q, agg);

    // ---- readout ----
    k_fill<<<8, 256, 0, stream>>>(hg, (long)(N_GRAPHS * D), INT_MIN);
    k_pool<<<POOL_GRID, 256, 0, stream>>>(agg, gid, hg);
    k_cls<<<1, 256, 0, stream>>>(hg, cls_w, cls_b, out);
}

// Round 9
// 245.393 us; speedup vs baseline: 3.2299x; 1.0373x over previous
//
#include <hip/hip_runtime.h>
#include <hip/hip_bf16.h>
#include <climits>

#define N_NODES   100000
#define N_EDGES   1600000
#define D         64
#define N_GRAPHS  32
#define N_CLASSES 40
#define N_TILES   (N_NODES / 16)   // 6250 row-tiles of 16
#define TPW       2                // row-tiles per wave
#define GEMM_WAVES ((N_TILES + TPW - 1) / TPW)        // 3125
#define GEMM_BLOCKS ((GEMM_WAVES + 3) / 4)            // 782
#define POOL_NPW  32               // nodes per wave in k_pool

// bucketed edge partition (bucket = 128 consecutive dst nodes)
#define BKT_SHIFT 7
#define BKT_NODES 128
#define NB        ((N_NODES + BKT_NODES - 1) / BKT_NODES)   // 782
#define CHUNK     4096
#define NCHUNK    ((N_EDGES + CHUNK - 1) / CHUNK)           // 391
#define EPT       (CHUNK / 256)                             // 16 edges/thread

typedef _Float16 f16_t;
typedef f16_t f16x8 __attribute__((ext_vector_type(8)));
typedef f16_t f16x4 __attribute__((ext_vector_type(4)));
typedef float  f32x4  __attribute__((ext_vector_type(4)));

// Monotone bijection float -> int (order-preserving for signed int compare).
__device__ __forceinline__ int f2ord(float f) {
    int i = __float_as_int(f);
    return (i >= 0) ? i : (i ^ 0x7FFFFFFF);
}
__device__ __forceinline__ float ord2f(int i) {
    int j = (i >= 0) ? i : (i ^ 0x7FFFFFFF);
    return __int_as_float(j);
}

__global__ __launch_bounds__(256) void k_fill(int* __restrict__ p, long n, int v) {
    long i = (long)blockIdx.x * blockDim.x + threadIdx.x;
    long stride = (long)gridDim.x * blockDim.x;
    for (; i < n; i += stride) p[i] = v;
}

// ---------------- weight prep: wcat[l][n][k] = (n<64 ? tw : pw)[l][k][n%64], f16 ----------------
__global__ __launch_bounds__(256) void k_prep(
    const float* __restrict__ tw, const float* __restrict__ pw,
    const float* __restrict__ tb, const float* __restrict__ pb,
    f16_t* __restrict__ wcat, float* __restrict__ bcat)
{
    const int i = blockIdx.x * 256 + threadIdx.x;
    if (i < 3 * 128 * 64) {
        const int l = i >> 13;
        const int rem = i & 8191;
        const int n = rem >> 6;
        const int k = rem & 63;
        const float v = (n < D) ? tw[l * 4096 + k * D + n] : pw[l * 4096 + k * D + (n - D)];
        wcat[i] = (f16_t)v;
    }
    if (i < 3 * D) bcat[i] = tb[i] + pb[i];
}

// ---------------- CSR build: bucket scatter (write-local) + in-bucket counting sort ----------------

__global__ __launch_bounds__(256) void k_bkt_hist(
    const int* __restrict__ dst, int* __restrict__ bktcnt)
{
    __shared__ int l[NB];
    for (int i = threadIdx.x; i < NB; i += 256) l[i] = 0;
    __syncthreads();
    const int base = blockIdx.x * CHUNK;
    #pragma unroll
    for (int i = 0; i < EPT; ++i) {
        const int e = base + i * 256 + threadIdx.x;
        if (e < N_EDGES) atomicAdd(&l[dst[e] >> BKT_SHIFT], 1);
    }
    __syncthreads();
    for (int i = threadIdx.x; i < NB; i += 256)
        if (l[i]) atomicAdd(&bktcnt[i], l[i]);
}

// Exclusive scan of NB bucket counts (1 block); also inits gcur and boff[NB].
__global__ __launch_bounds__(256) void k_bkt_scan(
    const int* __restrict__ bktcnt, int* __restrict__ boff, int* __restrict__ gcur,
    int* __restrict__ rowptr)
{
    __shared__ int s[256];
    const int t = threadIdx.x;
    int v[4], sum = 0;
    #pragma unroll
    for (int i = 0; i < 4; ++i) {
        const int idx = t * 4 + i;
        v[i] = (idx < NB) ? bktcnt[idx] : 0;
        sum += v[i];
    }
    s[t] = sum;
    __syncthreads();
    #pragma unroll
    for (int off = 1; off < 256; off <<= 1) {
        int x = (t >= off) ? s[t - off] : 0;
        __syncthreads();
        s[t] += x;
        __syncthreads();
    }
    int run = s[t] - sum;
    #pragma unroll
    for (int i = 0; i < 4; ++i) {
        const int idx = t * 4 + i;
        if (idx < NB) {
            boff[idx] = run;
            gcur[idx] = run;
        }
        run += v[i];
    }
    if (t == 255) {
        boff[NB] = N_EDGES;
        rowptr[N_NODES] = N_EDGES;
    }
}

// Pass A: scatter edges into bucket regions. Block-local ranks via LDS, one global
// atomicAdd per (block,bucket) reserves a contiguous run -> write locality.
// Packed edge: (dst & 127) << 17 | src   (src < 2^17).
__global__ __launch_bounds__(256) void k_bkt_scatter(
    const int* __restrict__ src, const int* __restrict__ dst,
    int* __restrict__ gcur, unsigned* __restrict__ bke)
{
    __shared__ int lcnt[NB];
    __shared__ int gb[NB];
    for (int i = threadIdx.x; i < NB; i += 256) lcnt[i] = 0;
    __syncthreads();
    const int base = blockIdx.x * CHUNK;
    unsigned pk[EPT], br[EPT];
    #pragma unroll
    for (int i = 0; i < EPT; ++i) {
        const int e = base + i * 256 + threadIdx.x;
        if (e < N_EDGES) {
            const int d = dst[e];
            const int b = d >> BKT_SHIFT;
            const int r = atomicAdd(&lcnt[b], 1);
            pk[i] = ((unsigned)(d & (BKT_NODES - 1)) << 17) | (unsigned)src[e];
            br[i] = ((unsigned)b << 13) | (unsigned)r;   // r < 4096
        } else {
            br[i] = 0xFFFFFFFFu;
        }
    }
    __syncthreads();
    for (int i = threadIdx.x; i < NB; i += 256) {
        const int c = lcnt[i];
        gb[i] = c ? atomicAdd(&gcur[i], c) : 0;
    }
    __syncthreads();
    #pragma unroll
    for (int i = 0; i < EPT; ++i) {
        if (br[i] != 0xFFFFFFFFu) {
            const int b = br[i] >> 13;
            const int r = br[i] & 8191;
            bke[gb[b] + r] = pk[i];
        }
    }
}

// Pass B: in-bucket counting sort -> per-node CSR order + rowptr.
__global__ __launch_bounds__(256) void k_bkt_sort(
    const int* __restrict__ boff, const unsigned* __restrict__ bke,
    int* __restrict__ ebuf, int* __restrict__ rowptr)
{
    __shared__ int cnt[BKT_NODES];   // histogram, then cursor
    __shared__ int pfx[BKT_NODES];   // inclusive scan
    const int b = blockIdx.x;
    const int tid = threadIdx.x;
    const int beg = boff[b];
    const int end = boff[b + 1];

    if (tid < BKT_NODES) cnt[tid] = 0;
    __syncthreads();
    for (int e = beg + tid; e < end; e += 256)
        atomicAdd(&cnt[bke[e] >> 17], 1);
    __syncthreads();
    if (tid < BKT_NODES) pfx[tid] = cnt[tid];
    __syncthreads();
    #pragma unroll
    for (int off = 1; off < BKT_NODES; off <<= 1) {
        int x = 0;
        if (tid < BKT_NODES && tid >= off) x = pfx[tid - off];
        __syncthreads();
        if (tid < BKT_NODES) pfx[tid] += x;
        __syncthreads();
    }
    if (tid < BKT_NODES) {
        const int excl = pfx[tid] - cnt[tid];
        const int node = b * BKT_NODES + tid;
        if (node <= N_NODES) rowptr[node] = beg + excl;
        cnt[tid] = beg + excl;
    }
    __syncthreads();
    for (int e = beg + tid; e < end; e += 256) {
        const unsigned pk = bke[e];
        const int pos = atomicAdd(&cnt[pk >> 17], 1);
        ebuf[pos] = (int)(pk & 0x1FFFFu);
    }
}

// ---------------- fused node GEMM via MFMA (f16), operands SWAPPED ----------------
// mfma(bfrag, afrag, acc): A-operand = wcat rows (features), B-operand = node rows.
// D per lane: node = lane&15 (within tile), features c*16 + (lane>>4)*4 + j  -> f16x4 packed stores.
template <bool FROM_F32>
__global__ __launch_bounds__(256) void k_gemm_mfma(
    const float* __restrict__ hf, const f16_t* __restrict__ hb,
    const f16_t* __restrict__ wcat,  // [128][64] this layer
    const float* __restrict__ bcat,  // [64] this layer
    f16_t* __restrict__ t, f16_t* __restrict__ q)
{
    const int lane = threadIdx.x & 63;
    const int wid  = blockIdx.x * 4 + (threadIdx.x >> 6);
    const int r16  = lane & 15;
    const int kg   = lane >> 4;   // 0..3
    const int koff = kg * 8;

    f16x8 bfrag[8][2];
    #pragma unroll
    for (int c = 0; c < 8; ++c)
        #pragma unroll
        for (int s = 0; s < 2; ++s)
            bfrag[c][s] = *(const f16x8*)&wcat[(c * 16 + r16) * D + s * 32 + koff];

    f32x4 bias4[4];
    #pragma unroll
    for (int c = 0; c < 4; ++c) bias4[c] = *(const f32x4*)&bcat[c * 16 + kg * 4];

    #pragma unroll
    for (int tt = 0; tt < TPW; ++tt) {
        const int tile = wid * TPW + tt;
        if (tile >= N_TILES) return;
        const long rowbase = (long)tile * 16;
        const long arow = rowbase + r16;

        f16x8 afrag[2];
        if (FROM_F32) {
            #pragma unroll
            for (int s = 0; s < 2; ++s) {
                const f32x4 v0 = *(const f32x4*)&hf[arow * D + s * 32 + koff];
                const f32x4 v1 = *(const f32x4*)&hf[arow * D + s * 32 + koff + 4];
                f16x8 a;
                a[0] = (f16_t)v0[0]; a[1] = (f16_t)v0[1];
                a[2] = (f16_t)v0[2]; a[3] = (f16_t)v0[3];
                a[4] = (f16_t)v1[0]; a[5] = (f16_t)v1[1];
                a[6] = (f16_t)v1[2]; a[7] = (f16_t)v1[3];
                afrag[s] = a;
            }
        } else {
            afrag[0] = *(const f16x8*)&hb[arow * D + koff];
            afrag[1] = *(const f16x8*)&hb[arow * D + 32 + koff];
        }

        const f32x4 zero = {0.0f, 0.0f, 0.0f, 0.0f};
        f32x4 acc[8];
        #pragma unroll
        for (int c = 0; c < 8; ++c) {
            acc[c] = __builtin_amdgcn_mfma_f32_16x16x32_f16(bfrag[c][0], afrag[0], zero, 0, 0, 0);
            acc[c] = __builtin_amdgcn_mfma_f32_16x16x32_f16(bfrag[c][1], afrag[1], acc[c], 0, 0, 0);
        }

        // lane holds node (rowbase + r16), features c*16 + kg*4 + j
        const long node = rowbase + r16;
        #pragma unroll
        for (int c = 0; c < 4; ++c) {
            f16x4 tv, qv;
            #pragma unroll
            for (int j = 0; j < 4; ++j) {
                const float tf = acc[c][j];
                tv[j] = (f16_t)tf;
                qv[j] = (f16_t)(acc[c + 4][j] - tf + bias4[c][j]);
            }
            *(f16x4*)&t[node * D + c * 16 + kg * 4] = tv;
            *(f16x4*)&q[node * D + c * 16 + kg * 4] = qv;
        }
    }
}

// ---------------- gather-max: 8 nodes per wave, one 8-lane group per node ----------------
// Lane g = lane&7 covers features g*8..g*8+7 (16 B). No cross-lane reduce needed.
// Clamped duplicate loads are idempotent under max.
__global__ __launch_bounds__(256) void k_edge_csr(
    const int* __restrict__ rowptr, const int* __restrict__ ebuf,
    const f16_t* __restrict__ t, const f16_t* __restrict__ q,
    f16_t* __restrict__ agg)
{
    const int lane = threadIdx.x & 63;
    const int grp  = lane >> 3;     // node sub-index 0..7
    const int g    = lane & 7;      // feature group
    const int node = (blockIdx.x * 4 + (threadIdx.x >> 6)) * 8 + grp;
    const int beg = rowptr[node];
    const int end = rowptr[node + 1];
    const long nrow = (long)node * D + g * 8;

    if (end == beg) {               // no in-edges: DGL zero-fill
        f16x8 z;
        #pragma unroll
        for (int i = 0; i < 8; ++i) z[i] = (f16_t)0.0f;
        *(f16x8*)&agg[nrow] = z;
        return;
    }

    const int last = end - 1;
    f16x8 m0, m1;
    {
        int r[8];
        #pragma unroll
        for (int u = 0; u < 8; ++u) r[u] = ebuf[min(beg + u, last)];
        f16x8 v[8];
        #pragma unroll
        for (int u = 0; u < 8; ++u) v[u] = *(const f16x8*)&t[((long)r[u] << 6) + g * 8];
        m0 = __builtin_elementwise_max(__builtin_elementwise_max(v[0], v[1]),
                                       __builtin_elementwise_max(v[2], v[3]));
        m1 = __builtin_elementwise_max(__builtin_elementwise_max(v[4], v[5]),
                                       __builtin_elementwise_max(v[6], v[7]));
    }
    for (int e0 = beg + 8; e0 < end; e0 += 8) {
        int r[8];
        #pragma unroll
        for (int u = 0; u < 8; ++u) r[u] = ebuf[min(e0 + u, last)];
        f16x8 v[8];
        #pragma unroll
        for (int u = 0; u < 8; ++u) v[u] = *(const f16x8*)&t[((long)r[u] << 6) + g * 8];
        m0 = __builtin_elementwise_max(m0,
                 __builtin_elementwise_max(__builtin_elementwise_max(v[0], v[1]),
                                           __builtin_elementwise_max(v[2], v[3])));
        m1 = __builtin_elementwise_max(m1,
                 __builtin_elementwise_max(__builtin_elementwise_max(v[4], v[5]),
                                           __builtin_elementwise_max(v[6], v[7])));
    }
    const f16x8 m = __builtin_elementwise_max(m0, m1);
    const f16x8 qv = *(const f16x8*)&q[nrow];
    *(f16x8*)&agg[nrow] = m + qv;
}

// ---------------- readout ----------------
__global__ __launch_bounds__(256) void k_pool(
    const f16_t* __restrict__ agg, const int* __restrict__ gid,
    int* __restrict__ hg)
{
    const int lane = threadIdx.x & 63;
    const int wave = threadIdx.x >> 6;
    const int n0 = (blockIdx.x * 4 + wave) * POOL_NPW;
    if (n0 >= N_NODES) return;
    const int nend = (n0 + POOL_NPW < N_NODES) ? n0 + POOL_NPW : N_NODES;
    int cur = gid[n0];
    float m = -INFINITY;
    for (int n = n0; n < nend; ++n) {
        const int g = gid[n];
        if (g != cur) {
            atomicMax(&hg[cur * D + lane], f2ord(m));
            cur = g;
            m = -INFINITY;
        }
        m = fmaxf(m, (float)agg[(long)n * D + lane]);
    }
    atomicMax(&hg[cur * D + lane], f2ord(m));
}

__global__ __launch_bounds__(256) void k_cls(
    const int* __restrict__ hg, const float* __restrict__ w,
    const float* __restrict__ b, float* __restrict__ out)
{
    __shared__ float s_h[N_GRAPHS * D];
    __shared__ float s_w[D * N_CLASSES];
    __shared__ float s_b[N_CLASSES];
    for (int i = threadIdx.x; i < N_GRAPHS * D; i += 256) s_h[i] = ord2f(hg[i]);
    for (int i = threadIdx.x; i < D * N_CLASSES; i += 256) s_w[i] = w[i];
    if (threadIdx.x < N_CLASSES) s_b[threadIdx.x] = b[threadIdx.x];
    __syncthreads();
    for (int o = threadIdx.x; o < N_GRAPHS * N_CLASSES; o += 256) {
        const int g = o / N_CLASSES;
        const int c = o % N_CLASSES;
        float acc = s_b[c];
        #pragma unroll
        for (int k = 0; k < D; ++k)
            acc = fmaf(s_h[g * D + k], s_w[k * N_CLASSES + c], acc);
        out[o] = acc;
    }
}

extern "C" void kernel_launch(void* const* d_in, const int* in_sizes, int n_in,
                              void* d_out, int out_size, void* d_ws, size_t ws_size,
                              hipStream_t stream) {
    const float* h       = (const float*)d_in[0];
    const int*   src     = (const int*)d_in[1];
    const int*   dst     = (const int*)d_in[2];
    const int*   gid     = (const int*)d_in[3];
    const float* theta_w = (const float*)d_in[4];
    const float* theta_b = (const float*)d_in[5];
    const float* phi_w   = (const float*)d_in[6];
    const float* phi_b   = (const float*)d_in[7];
    const float* cls_w   = (const float*)d_in[8];
    const float* cls_b   = (const float*)d_in[9];
    float* out = (float*)d_out;

    const size_t NF = (size_t)N_NODES * D;
    char* p = (char*)d_ws;
    f16_t* t     = (f16_t*)p;   p += NF * 2;                 // 12.8 MB
    f16_t* q     = (f16_t*)p;   p += NF * 2;                 // 12.8 MB
    f16_t* agg   = (f16_t*)p;   p += NF * 2;                 // 12.8 MB
    f16_t* wcat  = (f16_t*)p;   p += 3 * 128 * D * 2;        // 48 KB
    float*  bcat = (float*)p;   p += 3 * D * 4;
    unsigned* bke = (unsigned*)p; p += (size_t)N_EDGES * 4;  // 6.4 MB
    int* ebuf    = (int*)p;     p += (size_t)N_EDGES * 4;    // 6.4 MB
    int* rowptr  = (int*)p;     p += (N_NODES + 1) * 4;
    int* bktcnt  = (int*)p;     p += NB * 4;
    int* boff    = (int*)p;     p += (NB + 1) * 4;
    int* gcur    = (int*)p;     p += NB * 4;
    int* hg      = (int*)p;     p += N_GRAPHS * D * 4;
    const size_t need = (size_t)(p - (char*)d_ws);
    if (ws_size < need) {
        hipMemsetAsync(d_out, 0, (size_t)out_size * sizeof(float), stream);
        return;
    }

    const int EDGE_GRID = N_NODES / 32;                                   // 3125 (8 nodes/wave)
    const int POOL_GRID = (N_NODES + POOL_NPW * 4 - 1) / (POOL_NPW * 4);  // 782

    // ---- prep: transposed f16 weights + fused biases ----
    k_prep<<<96, 256, 0, stream>>>(theta_w, phi_w, theta_b, phi_b, wcat, bcat);

    // ---- CSR build: bucket scatter + in-bucket counting sort (once; all 3 layers) ----
    k_fill<<<4, 256, 0, stream>>>(bktcnt, NB, 0);
    k_bkt_hist<<<NCHUNK, 256, 0, stream>>>(dst, bktcnt);
    k_bkt_scan<<<1, 256, 0, stream>>>(bktcnt, boff, gcur, rowptr);
    k_bkt_scatter<<<NCHUNK, 256, 0, stream>>>(src, dst, gcur, bke);
    k_bkt_sort<<<NB, 256, 0, stream>>>(boff, bke, ebuf, rowptr);

    // ---- 3 EdgeConv layers ----
    k_gemm_mfma<true><<<GEMM_BLOCKS, 256, 0, stream>>>(h, nullptr, wcat, bcat, t, q);
    k_edge_csr<<<EDGE_GRID, 256, 0, stream>>>(rowptr, ebuf, t, q, agg);

    k_gemm_mfma<false><<<GEMM_BLOCKS, 256, 0, stream>>>(
        nullptr, agg, wcat + 128 * D, bcat + D, t, q);
    k_edge_csr<<<EDGE_GRID, 256, 0, stream>>>(rowptr, ebuf, t, q, agg);

    k_gemm_mfma<false><<<GEMM_BLOCKS, 256, 0, stream>>>(
        nullptr, agg, wcat + 2 * 128 * D, bcat + 2 * D, t, q);
    k_edge_csr<<<EDGE_GRID, 256, 0, stream>>>(rowptr, ebuf, t, q, agg);

    // ---- readout ----
    k_fill<<<8, 256, 0, stream>>>(hg, (long)(N_GRAPHS * D), INT_MIN);
    k_pool<<<POOL_GRID, 256, 0, stream>>>(agg, gid, hg);
    k_cls<<<1, 256, 0, stream>>>(hg, cls_w, cls_b, out);
}